// Round 16
// baseline (4306.430 us; speedup 1.0000x reference)
//
#include <hip/hip_runtime.h>

typedef _Float16 half8 __attribute__((ext_vector_type(8)));
typedef float floatx4 __attribute__((ext_vector_type(4)));
typedef unsigned int uintx4 __attribute__((ext_vector_type(4)));
typedef unsigned long long u64t;

#define S_ 512
#define H_ 1024

// Launch epoch base in .bss (zero at load). Block 0 bumps +1024 (> S_+1) at
// kernel END. Co-residency (cooperative / capacity) + each group's lockstep
// progress guarantee every block's start-read precedes any block's end-bump
// (a group can only advance if all 64 members publish, and publishing
// follows the start-read).  [r9/r12-proven]
__device__ unsigned tagctr;

__device__ __forceinline__ float sigmoidf_(float x) { return 1.0f / (1.0f + __expf(-x)); }
__device__ __forceinline__ float tanhf_(float x) {
    return 1.0f - 2.0f / (__expf(2.0f * x) + 1.0f);
}

// 512 blocks x 256 threads, 2 blocks/CU. gid = bid&7 (group; = XCD if
// dispatch round-robins bid%8), cbk = bid>>3 (0..63). Group owns batches
// [8gid, 8gid+8); block owns cols [16cbk,16cbk+16), full K=1024; wave =
// K-quarter; K-reduce in double-buffered LDS (one __syncthreads per step).
// M=8: A rows 8..15 duplicate rows 0..7 (C rows 8..15 discarded).
//
// Transport: tagged-payload dataflow (r12-proven), DUAL-stored:
//   LOCAL region: plain store -> producer XCD's L2 (updates the shared cache)
//   MIRROR region: agent sc1 store -> LLC (always-correct fallback)
// Consumer: forced 16x global_load_dwordx4 sc0 burst on LOCAL (L1-bypass,
// L2-hit if same XCD); tags validate; on miss re-burst MIRROR with sc1
// (r12-proven). Placement/cache-semantics assumptions affect ONLY speed:
// any stale/early read fails the tag check and falls through.
// WAR safety (r12 proof verbatim): publish(t+1) follows the reduce-sync
// which follows consuming step t from ALL 64 group blocks; a block publishes
// t only after finishing its reads of buffer[(t-1)&1] = buffer[(t+1)&1].
__global__ void __launch_bounds__(256, 2)
lstm_scan(const float* __restrict__ emb, const float* __restrict__ W, const float* __restrict__ bW,
          const float* __restrict__ U, const float* __restrict__ bU,
          const float* __restrict__ V, const float* __restrict__ bV,
          float* __restrict__ out, unsigned char* __restrict__ ws)
{
    const int bid  = blockIdx.x;
    const int gid  = bid & 7;     // group (intended = XCD)
    const int cbk  = bid >> 3;    // column block 0..63
    const int tid  = threadIdx.x;
    const int w    = tid >> 6;    // wave = K-quarter
    const int lane = tid & 63;
    const int fr   = lane & 15;   // A-frag row index (0..15)
    const int kg   = lane >> 4;   // A-frag k-block
    const int rowA = fr & 7;      // valid payload row (rows 8..15 duplicate)

    // LOCAL [8 groups][2 buf][8 rows][512 words] u64 = 512 KB; MIRROR at +512 KB
    u64t* loc = (u64t*)ws + (unsigned)gid * (2 * 8 * 512);
    u64t* mir = (u64t*)(ws + 512 * 1024) + (unsigned)gid * (2 * 8 * 512);

    __shared__ __align__(16) float part[2][4 * 3 * 64 * 4];   // 24 KB

    const unsigned e0 = __hip_atomic_load(&tagctr, __ATOMIC_RELAXED,
                                          __HIP_MEMORY_SCOPE_AGENT);

    // ---- persistent weight fragments (f16, registers): 3 gates x 8 ksteps ----
    // B-frag: lane l holds B[k=(l>>4)*8+e][n=l&15], B[k][n]=Wgate[16cbk+n][k].
    half8 Bf[3][8];
    {
        const int jrow = cbk * 16 + fr;
        const int kb   = w * 256 + kg * 8;
        const float* p0 = W + jrow * H_ + kb;
        const float* p1 = U + jrow * H_ + kb;
        const float* p2 = V + jrow * H_ + kb;
        #pragma unroll
        for (int ks = 0; ks < 8; ++ks) {
            half8 h0, h1, h2;
            #pragma unroll
            for (int e = 0; e < 8; ++e) {
                h0[e] = (_Float16)p0[ks * 32 + e];
                h1[e] = (_Float16)p1[ks * 32 + e];
                h2[e] = (_Float16)p2[ks * 32 + e];
            }
            Bf[0][ks] = h0; Bf[1][ks] = h1; Bf[2][ks] = h2;
        }
    }

    // ---- elementwise ownership: threads 0..127 -> cell (b, j) ----
    const int  rt     = tid >> 4;          // 0..15; valid rows 0..7
    const int  ct     = tid & 15;
    const bool active = (tid < 128);       // waves 0,1 handle the 8x16 tile
    const int  b      = gid * 8 + (rt & 7);
    const int  j      = cbk * 16 + ct;
    const float bw = bW[j], bu = bU[j], bv = bV[j];
    const int rl = ((rt & 7) >> 2) * 16 + ct;  // C/D source lane (rows 0..7)
    const int rr = rt & 3;                     // C/D source reg
    const bool evenct = (ct & 1) == 0;

    // publish: {tag32 | f16(c), f16(c+1)} 8B word, stored to LOCAL (plain)
    // and MIRROR (sc1). Fire-and-forget; tags gate consumption.
    auto publish = [&](int buf, unsigned tag, float xin) {
        union { _Float16 h; unsigned short u; } cvp; cvp.h = (_Float16)xin;
        unsigned mine  = cvp.u;
        unsigned other = (unsigned)__shfl_xor((int)mine, 1);
        if (evenct) {
            u64t v = ((u64t)tag << 32) | (u64t)(mine | (other << 16));
            unsigned widx = (unsigned)(buf * (8 * 512) + (rt & 7) * 512 + cbk * 8 + (ct >> 1));
            asm volatile("global_store_dwordx2 %0, %1, off" :: "v"(loc + widx), "v"(v) : "memory");
            __hip_atomic_store(mir + widx, v, __ATOMIC_RELAXED, __HIP_MEMORY_SCOPE_AGENT);
        }
    };

    float p1s = 0.0f;
    float xio = 0.0f, embn = 0.0f;
    if (active) {
        xio = emb[(b * S_ + 0) * H_ + j];      // p2 init = 0
        publish(0, e0 + 1u, xio);
        embn = emb[(b * S_ + 1) * H_ + j];
    }

    for (int t = 0; t < S_; ++t) {
        const unsigned tag = e0 + (unsigned)t + 1u;
        const unsigned wbase = (unsigned)((t & 1) * (8 * 512) + rowA * 512 + w * 128 + kg * 4);
        const char* lb = (const char*)(loc + wbase);
        const char* mb = (const char*)(mir + wbase);

        uintx4 l0, l1, l2, l3, l4, l5, l6, l7, l8, l9, lA, lB, lC, lD, lE, lF;
        #define BURST(P, SC)                                                               \
            asm volatile("global_load_dwordx4 %0, %1, off " SC              : "=v"(l0) : "v"(P)); \
            asm volatile("global_load_dwordx4 %0, %1, off offset:16 " SC    : "=v"(l1) : "v"(P)); \
            asm volatile("global_load_dwordx4 %0, %1, off offset:128 " SC   : "=v"(l2) : "v"(P)); \
            asm volatile("global_load_dwordx4 %0, %1, off offset:144 " SC   : "=v"(l3) : "v"(P)); \
            asm volatile("global_load_dwordx4 %0, %1, off offset:256 " SC   : "=v"(l4) : "v"(P)); \
            asm volatile("global_load_dwordx4 %0, %1, off offset:272 " SC   : "=v"(l5) : "v"(P)); \
            asm volatile("global_load_dwordx4 %0, %1, off offset:384 " SC   : "=v"(l6) : "v"(P)); \
            asm volatile("global_load_dwordx4 %0, %1, off offset:400 " SC   : "=v"(l7) : "v"(P)); \
            asm volatile("global_load_dwordx4 %0, %1, off offset:512 " SC   : "=v"(l8) : "v"(P)); \
            asm volatile("global_load_dwordx4 %0, %1, off offset:528 " SC   : "=v"(l9) : "v"(P)); \
            asm volatile("global_load_dwordx4 %0, %1, off offset:640 " SC   : "=v"(lA) : "v"(P)); \
            asm volatile("global_load_dwordx4 %0, %1, off offset:656 " SC   : "=v"(lB) : "v"(P)); \
            asm volatile("global_load_dwordx4 %0, %1, off offset:768 " SC   : "=v"(lC) : "v"(P)); \
            asm volatile("global_load_dwordx4 %0, %1, off offset:784 " SC   : "=v"(lD) : "v"(P)); \
            asm volatile("global_load_dwordx4 %0, %1, off offset:896 " SC   : "=v"(lE) : "v"(P)); \
            asm volatile("global_load_dwordx4 %0, %1, off offset:912 " SC   : "=v"(lF) : "v"(P)); \
            asm volatile("s_waitcnt vmcnt(0)" ::: "memory");                                      \
            __builtin_amdgcn_sched_barrier(0);
        #define TAGOK(ok)                                                                  \
            bool ok = (l0[1] == tag) & (l0[3] == tag) & (l1[1] == tag) & (l1[3] == tag)    \
                    & (l2[1] == tag) & (l2[3] == tag) & (l3[1] == tag) & (l3[3] == tag)    \
                    & (l4[1] == tag) & (l4[3] == tag) & (l5[1] == tag) & (l5[3] == tag)    \
                    & (l6[1] == tag) & (l6[3] == tag) & (l7[1] == tag) & (l7[3] == tag)    \
                    & (l8[1] == tag) & (l8[3] == tag) & (l9[1] == tag) & (l9[3] == tag)    \
                    & (lA[1] == tag) & (lA[3] == tag) & (lB[1] == tag) & (lB[3] == tag)    \
                    & (lC[1] == tag) & (lC[3] == tag) & (lD[1] == tag) & (lD[3] == tag)    \
                    & (lE[1] == tag) & (lE[3] == tag) & (lF[1] == tag) & (lF[3] == tag);

        for (;;) {
            // 1) LOCAL attempt: sc0 (L1-bypass, hits shared L2 if same XCD)
            { BURST(lb, "sc0"); TAGOK(ok); if (__all(ok)) break; }
            // 2) MIRROR fallback: sc1 (LLC; r12-proven always-correct)
            { BURST(mb, "sc1"); TAGOK(ok); if (__all(ok)) break; }
            __builtin_amdgcn_s_sleep(1);
        }
        #undef BURST
        #undef TAGOK

        // ---- MFMA from captured registers (r12-proven extraction) ----
        floatx4 a0 = {0.f, 0.f, 0.f, 0.f};
        floatx4 a1 = {0.f, 0.f, 0.f, 0.f};
        floatx4 a2 = {0.f, 0.f, 0.f, 0.f};
        union { unsigned u[4]; half8 h; } cv;
        #define DO_KS(ks, A, Bv)                                                           \
        {                                                                                  \
            cv.u[0] = A[0]; cv.u[1] = A[2]; cv.u[2] = Bv[0]; cv.u[3] = Bv[2];              \
            a0 = __builtin_amdgcn_mfma_f32_16x16x32_f16(cv.h, Bf[0][ks], a0, 0, 0, 0);     \
            a1 = __builtin_amdgcn_mfma_f32_16x16x32_f16(cv.h, Bf[1][ks], a1, 0, 0, 0);     \
            a2 = __builtin_amdgcn_mfma_f32_16x16x32_f16(cv.h, Bf[2][ks], a2, 0, 0, 0);     \
        }
        DO_KS(0, l0, l1) DO_KS(1, l2, l3) DO_KS(2, l4, l5) DO_KS(3, l6, l7)
        DO_KS(4, l8, l9) DO_KS(5, lA, lB) DO_KS(6, lC, lD) DO_KS(7, lE, lF)
        #undef DO_KS

        // ---- K-reduction in LDS (double-buffered, one sync) ----
        float* pp = part[t & 1];
        *(floatx4*)&pp[((w * 3 + 0) * 64 + lane) * 4] = a0;
        *(floatx4*)&pp[((w * 3 + 1) * 64 + lane) * 4] = a1;
        *(floatx4*)&pp[((w * 3 + 2) * 64 + lane) * 4] = a2;
        __syncthreads();

        if (active) {
            float pf = bw, pu = bu, pv = bv;
            #pragma unroll
            for (int wv = 0; wv < 4; ++wv) {
                pf += pp[((wv * 3 + 0) * 64 + rl) * 4 + rr];
                pu += pp[((wv * 3 + 1) * 64 + rl) * 4 + rr];
                pv += pp[((wv * 3 + 2) * 64 + rl) * 4 + rr];
            }
            float fg = sigmoidf_(pf);
            float ig = sigmoidf_(pu);
            float gg = tanhf_(pv);
            p1s = fg * p1s + ig * gg;
            float p2 = sigmoidf_(xio) * tanhf_(p1s);

            if (t < S_ - 1) {
                float xin = embn + p2;
                xio = xin;
                publish((t + 1) & 1, e0 + (unsigned)t + 2u, xin);   // fire & forget
            }
            out[(b * S_ + t) * H_ + j] = p2;
            if (t + 2 < S_) embn = emb[(b * S_ + t + 2) * H_ + j];
        }
    }

    if (bid == 0 && tid == 0)
        __hip_atomic_store(&tagctr, e0 + 1024u, __ATOMIC_RELAXED,
                           __HIP_MEMORY_SCOPE_AGENT);
}

extern "C" void kernel_launch(void* const* d_in, const int* in_sizes, int n_in,
                              void* d_out, int out_size, void* d_ws, size_t ws_size,
                              hipStream_t stream)
{
    const float* emb = (const float*)d_in[0];
    const float* W   = (const float*)d_in[1];
    const float* bWv = (const float*)d_in[2];
    const float* U   = (const float*)d_in[3];
    const float* bUv = (const float*)d_in[4];
    const float* V   = (const float*)d_in[5];
    const float* bVv = (const float*)d_in[6];
    float* outp = (float*)d_out;
    unsigned char* ws = (unsigned char*)d_ws;
    (void)in_sizes; (void)n_in; (void)out_size; (void)ws_size;

    void* args[] = {(void*)&emb, (void*)&W, (void*)&bWv, (void*)&U, (void*)&bUv,
                    (void*)&V, (void*)&bVv, (void*)&outp, (void*)&ws};
    hipError_t err = hipLaunchCooperativeKernel((const void*)lstm_scan,
                                                dim3(512), dim3(256), args, 0, stream);
    if (err != hipSuccess) {
        // capacity allows full co-residency (2 blocks/CU); groups are
        // independent, so a plain launch is semantically identical.
        lstm_scan<<<dim3(512), dim3(256), 0, stream>>>(emb, W, bWv, U, bUv, V, bVv, outp, ws);
    }
}

// Round 17
// 1562.823 us; speedup vs baseline: 2.7555x; 2.7555x over previous
//
#include <hip/hip_runtime.h>

typedef _Float16 half8 __attribute__((ext_vector_type(8)));
typedef float floatx4 __attribute__((ext_vector_type(4)));
typedef unsigned int uintx4 __attribute__((ext_vector_type(4)));
typedef unsigned long long u64t;

#define B_ 64
#define S_ 512
#define H_ 1024

// Arrival slots, PADDED to one 64B line each (kills false sharing between
// pollers of different slots and lets the publisher's store land without
// queueing behind unrelated polls). .bss: zero at load, untouched by ws
// poison. Monotonic: each block's slot advances by exactly S_ per launch.
// Per-launch base e0 = own slot value read before any arrival. [r11-proven]
__device__ unsigned slotP[4][64][16];

__device__ __forceinline__ float sigmoidf_(float x) { return 1.0f / (1.0f + __expf(-x)); }
__device__ __forceinline__ float tanhf_(float x) {
    return 1.0f - 2.0f / (__expf(2.0f * x) + 1.0f);   // saturates correctly via __expf
}

// 256 blocks x 256 threads -- r11 structure/protocol VERBATIM (best measured:
// 2.22 ms) except the three slot-contention fixes:
//   1. slots padded to 64B lines (slotP)
//   2. single-poller: wave0 polls all 64 group slots (lane L <-> slot L),
//      waves 1-3 released by an added __syncthreads (stronger condition
//      than r11's per-wave 16-source poll -> all safety proofs carry over)
//   3. poll backoff s_sleep(8) (~0.2us) -> ~4x fewer poll round-trips
// Block (cb=bid&63, mb=bid>>6) owns the 16x16 tile, full K=1024; wave =
// K-quarter; K-reduce in double-buffered LDS (one reduce-__syncthreads);
// publish = packed 8B sc1 payload stores -> per-wave vmcnt(0) ->
// __syncthreads -> tid0 slot store; payload read = 8 forced asm dwordx4 sc1.
__global__ void __launch_bounds__(256, 1)
lstm_scan(const float* __restrict__ emb, const float* __restrict__ W, const float* __restrict__ bW,
          const float* __restrict__ U, const float* __restrict__ bU,
          const float* __restrict__ V, const float* __restrict__ bV,
          float* __restrict__ out, unsigned char* __restrict__ ws)
{
    const int bid  = blockIdx.x;
    const int cb   = bid & 63;    // column group (16 H-cols)
    const int mb   = bid >> 6;    // batch group (16 batches)
    const int tid  = threadIdx.x;
    const int w    = tid >> 6;    // wave id = K-quarter
    const int lane = tid & 63;
    const int fr   = lane & 15;   // A-frag row index
    const int kg   = lane >> 4;   // A-frag k-block

    u64t* pub  = (u64t*)ws;       // [2][64 rows][256 words] 4 f16/word = 256 KB
    char* pubc = (char*)ws;

    __shared__ __align__(16) float part[2][4 * 3 * 64 * 4];   // 2 x 12 KB

    const unsigned e0 = __hip_atomic_load(&slotP[mb][cb][0], __ATOMIC_RELAXED,
                                          __HIP_MEMORY_SCOPE_AGENT);

    // ---- persistent weight fragments (f16, registers): 3 gates x 8 ksteps ----
    // B-frag of mfma_f32_16x16x32_f16: lane l holds B[k=(l>>4)*8+e][n=l&15],
    // B[k][n] = Wgate[16*cb + n][k].  (Layout proven rounds 1/4-16.)
    half8 Bf[3][8];
    {
        const int jrow = cb * 16 + fr;
        const int kb   = w * 256 + kg * 8;
        const float* p0 = W + jrow * H_ + kb;
        const float* p1 = U + jrow * H_ + kb;
        const float* p2 = V + jrow * H_ + kb;
        #pragma unroll
        for (int ks = 0; ks < 8; ++ks) {
            half8 h0, h1, h2;
            #pragma unroll
            for (int e = 0; e < 8; ++e) {
                h0[e] = (_Float16)p0[ks * 32 + e];
                h1[e] = (_Float16)p1[ks * 32 + e];
                h2[e] = (_Float16)p2[ks * 32 + e];
            }
            Bf[0][ks] = h0; Bf[1][ks] = h1; Bf[2][ks] = h2;
        }
    }

    // ---- elementwise ownership: thread -> ONE cell (b, j) ----
    const int rt = tid >> 4;
    const int ct = tid & 15;
    const int b  = mb * 16 + rt;
    const int j  = cb * 16 + ct;
    const float bw = bW[j], bu = bU[j], bv = bV[j];
    const int rl = (rt >> 2) * 16 + ct;   // C/D source lane (proven)
    const int rr = rt & 3;                // C/D source reg

    // publish (r11 verbatim except padded slot): pack 4 f16 into one 8B sc1
    // word, drain, join waves, tid0 raises the block slot.
    auto publish = [&](int buf, unsigned slotval, float xin) {
        union { _Float16 h; unsigned short u; } cvp; cvp.h = (_Float16)xin;
        unsigned mine = cvp.u;
        unsigned lo = mine | ((unsigned)__shfl_xor((int)mine, 1) << 16);
        unsigned hi = (unsigned)__shfl_xor((int)lo, 2);
        if ((ct & 3) == 0)
            __hip_atomic_store(&pub[(unsigned)(buf * 16384 + b * 256 + cb * 4 + (ct >> 2))],
                               (u64t)lo | ((u64t)hi << 32),
                               __ATOMIC_RELAXED, __HIP_MEMORY_SCOPE_AGENT);
        asm volatile("s_waitcnt vmcnt(0)" ::: "memory");  // payload acked at LLC
        __syncthreads();
        if (tid == 0)
            __hip_atomic_store(&slotP[mb][cb][0], slotval, __ATOMIC_RELAXED,
                               __HIP_MEMORY_SCOPE_AGENT);
    };

    // single-poller wait: wave0 polls ALL 64 group slots (lane L -> slot L,
    // one padded line each); waves 1-3 are released by the barrier.
    auto waitall = [&](unsigned tgt) {
        if (tid < 64) {
            for (;;) {
                unsigned v = __hip_atomic_load(&slotP[mb][tid][0], __ATOMIC_RELAXED,
                                               __HIP_MEMORY_SCOPE_AGENT);
                if (__all((int)(v - tgt) >= 0)) break;
                __builtin_amdgcn_s_sleep(8);   // ~0.2us backoff
            }
        }
        asm volatile("" ::: "memory");
        __syncthreads();
    };

    float p1s = 0.0f;
    float xio = emb[(b * S_ + 0) * H_ + j];    // p2 init = 0
    publish(0, e0 + 1u, xio);
    float embn = emb[(b * S_ + 1) * H_ + j];   // prefetch t=1

    for (int t = 0; t < S_; ++t) {
        waitall(e0 + (unsigned)t + 1u);

        // ---- payload burst: 8 forced dwordx4 sc1 (one round-trip) [r11] ----
        const char* base = pubc + (unsigned)(((t & 1) * 64 + mb * 16 + fr) * 2048
                                             + w * 512 + kg * 16);
        uintx4 q0, q1, q2, q3, q4, q5, q6, q7;
        asm volatile("global_load_dwordx4 %0, %1, off sc1"            : "=v"(q0) : "v"(base));
        asm volatile("global_load_dwordx4 %0, %1, off offset:64 sc1"  : "=v"(q1) : "v"(base));
        asm volatile("global_load_dwordx4 %0, %1, off offset:128 sc1" : "=v"(q2) : "v"(base));
        asm volatile("global_load_dwordx4 %0, %1, off offset:192 sc1" : "=v"(q3) : "v"(base));
        asm volatile("global_load_dwordx4 %0, %1, off offset:256 sc1" : "=v"(q4) : "v"(base));
        asm volatile("global_load_dwordx4 %0, %1, off offset:320 sc1" : "=v"(q5) : "v"(base));
        asm volatile("global_load_dwordx4 %0, %1, off offset:384 sc1" : "=v"(q6) : "v"(base));
        asm volatile("global_load_dwordx4 %0, %1, off offset:448 sc1" : "=v"(q7) : "v"(base));
        asm volatile("s_waitcnt vmcnt(0)" ::: "memory");
        __builtin_amdgcn_sched_barrier(0);

        // ---- MFMA from captured registers [r11] ----
        floatx4 a0 = {0.f, 0.f, 0.f, 0.f};
        floatx4 a1 = {0.f, 0.f, 0.f, 0.f};
        floatx4 a2 = {0.f, 0.f, 0.f, 0.f};
        union { uintx4 v; half8 h; } cva;
        #define DO_KS(ks, Q)                                                          \
        {                                                                             \
            cva.v = Q; half8 Af = cva.h;                                              \
            a0 = __builtin_amdgcn_mfma_f32_16x16x32_f16(Af, Bf[0][ks], a0, 0, 0, 0);  \
            a1 = __builtin_amdgcn_mfma_f32_16x16x32_f16(Af, Bf[1][ks], a1, 0, 0, 0);  \
            a2 = __builtin_amdgcn_mfma_f32_16x16x32_f16(Af, Bf[2][ks], a2, 0, 0, 0);  \
        }
        DO_KS(0, q0) DO_KS(1, q1) DO_KS(2, q2) DO_KS(3, q3)
        DO_KS(4, q4) DO_KS(5, q5) DO_KS(6, q6) DO_KS(7, q7)
        #undef DO_KS

        // ---- K-reduction in LDS (double-buffered, one sync) [r11] ----
        float* pp = part[t & 1];
        *(floatx4*)&pp[((w * 3 + 0) * 64 + lane) * 4] = a0;
        *(floatx4*)&pp[((w * 3 + 1) * 64 + lane) * 4] = a1;
        *(floatx4*)&pp[((w * 3 + 2) * 64 + lane) * 4] = a2;
        __syncthreads();

        float pf = bw, pu = bu, pv = bv;
        #pragma unroll
        for (int wv = 0; wv < 4; ++wv) {
            pf += pp[((wv * 3 + 0) * 64 + rl) * 4 + rr];
            pu += pp[((wv * 3 + 1) * 64 + rl) * 4 + rr];
            pv += pp[((wv * 3 + 2) * 64 + rl) * 4 + rr];
        }

        // ---- gates + state update [r11] ----
        float fg = sigmoidf_(pf);
        float ig = sigmoidf_(pu);
        float gg = tanhf_(pv);
        p1s = fg * p1s + ig * gg;
        float p2 = sigmoidf_(xio) * tanhf_(p1s);

        if (t < S_ - 1) {
            float xin = embn + p2;
            xio = xin;
            publish((t + 1) & 1, e0 + (unsigned)t + 2u, xin);
            // after the slot store: these drain during other blocks' polls
            __builtin_nontemporal_store(p2, &out[(b * S_ + t) * H_ + j]);
            if (t + 2 < S_) embn = emb[(b * S_ + t + 2) * H_ + j];
        } else {
            __builtin_nontemporal_store(p2, &out[(b * S_ + t) * H_ + j]);
        }
    }
}

extern "C" void kernel_launch(void* const* d_in, const int* in_sizes, int n_in,
                              void* d_out, int out_size, void* d_ws, size_t ws_size,
                              hipStream_t stream)
{
    const float* emb = (const float*)d_in[0];
    const float* W   = (const float*)d_in[1];
    const float* bWv = (const float*)d_in[2];
    const float* U   = (const float*)d_in[3];
    const float* bUv = (const float*)d_in[4];
    const float* V   = (const float*)d_in[5];
    const float* bVv = (const float*)d_in[6];
    float* outp = (float*)d_out;
    unsigned char* ws = (unsigned char*)d_ws;
    (void)in_sizes; (void)n_in; (void)out_size; (void)ws_size;

    void* args[] = {(void*)&emb, (void*)&W, (void*)&bWv, (void*)&U, (void*)&bUv,
                    (void*)&V, (void*)&bVv, (void*)&outp, (void*)&ws};
    hipError_t err = hipLaunchCooperativeKernel((const void*)lstm_scan,
                                                dim3(256), dim3(256), args, 0, stream);
    if (err != hipSuccess) {
        lstm_scan<<<dim3(256), dim3(256), 0, stream>>>(emb, W, bWv, U, bUv, V, bVv, outp, ws);
    }
}